// Round 10
// baseline (165.185 us; speedup 1.0000x reference)
//
#include <hip/hip_runtime.h>
#include <hip/hip_fp16.h>

typedef _Float16 half8_t __attribute__((ext_vector_type(8)));
typedef _Float16 half4_t __attribute__((ext_vector_type(4)));
typedef float f32x4 __attribute__((ext_vector_type(4)));
typedef unsigned int u32x4 __attribute__((ext_vector_type(4)));

// ws: [0,55296)      w1T fp16 [288][96]; rows 0..95 = Q cols PERMUTED, scaled qs*log2e
//     [55296,73728)  w2T fp16 [96][96]
//     [73728,74880)  b1p f32 [288]
//     [74880,140416) tblP f32 [4][64][64] (permuted, *log2e)
//     [140416, +111149056)  KVg: per-window 27136B LDS image (Kb[64][104], Vt[96][72])
//     [111289472, +50331648) Qg: per-window 256 lanes x 48B packed Q B-frags
#define WS_W2T 55296
#define WS_B1P 73728
#define WS_TBL 74880
#define WS_KVG 140416
#define KV_BYTES 27136
#define WS_QG  111289472ULL
#define WS_NEED 161621120ULL

__global__ __launch_bounds__(256) void swin_prep_kernel(
    const float* __restrict__ w1, const float* __restrict__ b1,
    const float* __restrict__ w2, const float* __restrict__ relb,
    _Float16* __restrict__ w1T, _Float16* __restrict__ w2T,
    float* __restrict__ b1p, float* __restrict__ tblP)
{
    int idx = blockIdx.x * 256 + threadIdx.x;
    const float L2E = 1.4426950408889634f;
    const float qs2 = 0.17677669529663687f * L2E;
    if (idx < 27648) {
        int jp = idx / 96, k = idx % 96;
        float v;
        if (jp < 96) {
            int f = jp >> 4, m = jp & 15;
            int cq = (f >> 1) * 32 + (m >> 2) * 8 + (f & 1) * 4 + (m & 3);
            v = w1[k * 288 + cq * 3] * qs2;
        } else {
            int jo = (jp % 96) * 3 + (jp / 96);
            v = w1[k * 288 + jo];
        }
        w1T[idx] = (_Float16)v;
    } else if (idx < 36864) {
        int i2 = idx - 27648;
        int n = i2 / 96, k = i2 % 96;
        w2T[i2] = (_Float16)w2[k * 96 + n];
    } else if (idx < 37152) {
        int jp = idx - 36864;
        float v = b1[(jp % 96) * 3 + (jp / 96)];
        if (jp < 96) v *= qs2;
        b1p[jp] = v;
    } else if (idx < 53536) {
        int t = idx - 37152;
        int vv = t >> 12, q = (t >> 6) & 63, c = t & 63;
        int i = c >> 4, m = c & 15;
        int k = (i >> 1) * 32 + (m >> 2) * 8 + (i & 1) * 4 + (m & 3);
        float val = -1e30f;
        if (q < 49 && k < 49) {
            val = relb[q * 49 + k] * L2E;
            if ((vv & 1) && ((q >= 28) != (k >= 28))) val = -1e30f;
            if ((vv & 2) && (((q % 7) >= 4) != ((k % 7) >= 4))) val = -1e30f;
        }
        tblP[t] = val;
    }
}

__device__ __forceinline__ unsigned int pack2h(float a, float b) {
    union { _Float16 h[2]; unsigned int u; } p;
    p.h[0] = (_Float16)a; p.h[1] = (_Float16)b;
    return p.u;
}
__device__ __forceinline__ unsigned int pkrtz(float a, float b) {
    return __builtin_bit_cast(unsigned int, __builtin_amdgcn_cvt_pkrtz(a, b));
}

// ======== STAGE 1: QKV producer (R9 phases 0+1 verbatim; exports LDS image + Q frags) ========
__global__ __launch_bounds__(256) void swin_qkv_kernel(
    const float* __restrict__ x,
    const _Float16* __restrict__ w1T,
    const float* __restrict__ b1p,
    char* __restrict__ kvg, unsigned int* __restrict__ qg)
{
    __shared__ __align__(16) char smem[27136];
    _Float16* Kb = (_Float16*)smem;            // [64][104]
    _Float16* Vt = (_Float16*)(smem + 13312);  // [96][72]
    _Float16* Xs = Kb;

    const int tid = threadIdx.x;
    const int wv = tid >> 6, lane = tid & 63;
    const int lr = lane & 15, lg = lane >> 4;
    const int gid = blockIdx.x;
    const int b = gid >> 6, wh = (gid >> 3) & 7, ww = gid & 7;
    const f32x4 fz = {0.f, 0.f, 0.f, 0.f};

    {   // phase 0: rolled x gather -> Xs
        const int p = tid >> 2, sub = tid & 3;
        const float* xrow = nullptr;
        if (p < 49) {
            const int m1 = p / 7, m2 = p % 7;
            int rr = wh * 7 + m1 + 4; if (rr >= 56) rr -= 56;
            int cc = ww * 7 + m2 + 4; if (cc >= 56) cc -= 56;
            xrow = x + ((size_t)b * 3136 + rr * 56 + cc) * 96;
        }
        #pragma unroll
        for (int j = 0; j < 6; ++j) {
            const int e = sub * 24 + j * 4;
            half4_t hv = {(_Float16)0.f, (_Float16)0.f, (_Float16)0.f, (_Float16)0.f};
            if (p < 49) {
                const float4 v = *(const float4*)(xrow + e);
                hv[0] = (_Float16)v.x; hv[1] = (_Float16)v.y;
                hv[2] = (_Float16)v.z; hv[3] = (_Float16)v.w;
            }
            *(half4_t*)(Xs + p * 104 + e) = hv;
        }
    }
    __syncthreads();

    half8_t xa[4][3], xq[3];
    #pragma unroll
    for (int mt = 0; mt < 4; ++mt)
        #pragma unroll
        for (int kt = 0; kt < 3; ++kt)
            xa[mt][kt] = *(const half8_t*)(Xs + (mt * 16 + lr) * 104 + kt * 32 + lg * 8);
    #pragma unroll
    for (int kt = 0; kt < 3; ++kt)
        xq[kt] = *(const half8_t*)(Xs + (wv * 16 + lr) * 104 + kt * 32 + lg * 8);
    __syncthreads();

    {   // phase 1a: K,V (nt-split; permuted stores; prefetched)
        half8_t bf0, bf1, bf2; float bv;
        {
            const int nt0 = 6 + wv;
            bf0 = *(const half8_t*)(w1T + (nt0 * 16 + lr) * 96 + lg * 8);
            bf1 = *(const half8_t*)(w1T + (nt0 * 16 + lr) * 96 + 32 + lg * 8);
            bf2 = *(const half8_t*)(w1T + (nt0 * 16 + lr) * 96 + 64 + lg * 8);
            bv = b1p[nt0 * 16 + lr];
        }
        #pragma unroll
        for (int t = 0; t < 3; ++t) {
            const int nt = 6 + wv + 4 * t;
            half8_t nf0 = bf0, nf1 = bf1, nf2 = bf2; float nbv = bv;
            if (t < 2) {
                const int ntn = nt + 4;
                nf0 = *(const half8_t*)(w1T + (ntn * 16 + lr) * 96 + lg * 8);
                nf1 = *(const half8_t*)(w1T + (ntn * 16 + lr) * 96 + 32 + lg * 8);
                nf2 = *(const half8_t*)(w1T + (ntn * 16 + lr) * 96 + 64 + lg * 8);
                nbv = b1p[ntn * 16 + lr];
            }
            #pragma unroll
            for (int mt = 0; mt < 4; ++mt) {
                f32x4 acc = fz;
                acc = __builtin_amdgcn_mfma_f32_16x16x32_f16(xa[mt][0], bf0, acc, 0, 0, 0);
                acc = __builtin_amdgcn_mfma_f32_16x16x32_f16(xa[mt][1], bf1, acc, 0, 0, 0);
                acc = __builtin_amdgcn_mfma_f32_16x16x32_f16(xa[mt][2], bf2, acc, 0, 0, 0);
                if (nt < 12) {
                    const int kc = ((nt - 6) * 16 + lr) ^ ((lg & 1) << 4);
                    #pragma unroll
                    for (int r = 0; r < 4; ++r) {
                        const int krow = ((mt >> 1) * 2 + (lg & 1)) * 16
                                       + ((mt * 2 + (lg >> 1)) & 3) * 4 + r;
                        Kb[krow * 104 + kc] = (_Float16)(acc[r] + bv);
                    }
                } else {
                    const int nv = nt - 12;
                    const int hh = nv >> 1, eta = nv & 1;
                    const int vrow = hh * 32 + ((lr >> 2) & 1) * 16
                                   + (((eta << 1) + (lr >> 3)) & 3) * 4 + (lr & 3);
                    half4_t hv;
                    #pragma unroll
                    for (int r = 0; r < 4; ++r) hv[r] = (_Float16)(acc[r] + bv);
                    *(half4_t*)(Vt + vrow * 72 + mt * 16 + lg * 4) = hv;
                }
            }
            bf0 = nf0; bf1 = nf1; bf2 = nf2; bv = nbv;
        }
    }

    // phase 1b: Q B-frags -> qpk, straight to global (register path, no barrier dep)
    unsigned int qpk[3][4];
    {
        half8_t af0 = *(const half8_t*)(w1T + lr * 96 + lg * 8);
        half8_t af1 = *(const half8_t*)(w1T + lr * 96 + 32 + lg * 8);
        half8_t af2 = *(const half8_t*)(w1T + lr * 96 + 64 + lg * 8);
        #pragma unroll
        for (int f = 0; f < 6; ++f) {
            half8_t n0 = af0, n1 = af1, n2 = af2;
            if (f < 5) {
                n0 = *(const half8_t*)(w1T + ((f + 1) * 16 + lr) * 96 + lg * 8);
                n1 = *(const half8_t*)(w1T + ((f + 1) * 16 + lr) * 96 + 32 + lg * 8);
                n2 = *(const half8_t*)(w1T + ((f + 1) * 16 + lr) * 96 + 64 + lg * 8);
            }
            f32x4 acc = fz;
            acc = __builtin_amdgcn_mfma_f32_16x16x32_f16(af0, xq[0], acc, 0, 0, 0);
            acc = __builtin_amdgcn_mfma_f32_16x16x32_f16(af1, xq[1], acc, 0, 0, 0);
            acc = __builtin_amdgcn_mfma_f32_16x16x32_f16(af2, xq[2], acc, 0, 0, 0);
            const float4 bq = *(const float4*)(b1p + (f >> 1) * 32 + lg * 8 + (f & 1) * 4);
            qpk[f >> 1][(f & 1) * 2 + 0] = pack2h(acc[0] + bq.x, acc[1] + bq.y);
            qpk[f >> 1][(f & 1) * 2 + 1] = pack2h(acc[2] + bq.z, acc[3] + bq.w);
            af0 = n0; af1 = n1; af2 = n2;
        }
    }
    {
        unsigned int* qdst = qg + (size_t)gid * 3072 + tid * 12;
        *(u32x4*)(qdst + 0) = (u32x4){qpk[0][0], qpk[0][1], qpk[0][2], qpk[0][3]};
        *(u32x4*)(qdst + 4) = (u32x4){qpk[1][0], qpk[1][1], qpk[1][2], qpk[1][3]};
        *(u32x4*)(qdst + 8) = (u32x4){qpk[2][0], qpk[2][1], qpk[2][2], qpk[2][3]};
    }
    __syncthreads();   // K/V LDS complete

    // bulk copy LDS image -> KVg (coalesced b128)
    {
        char* dst = kvg + (size_t)gid * KV_BYTES;
        #pragma unroll
        for (int i = 0; i < 7; ++i) {
            const int idx = tid + i * 256;
            if (idx < 1696)
                *(float4*)(dst + idx * 16) = *(const float4*)(smem + idx * 16);
        }
    }
}

// ======== STAGE 2: attention consumer (blob -> LDS, R9 head-loop, store) ========
__global__ __launch_bounds__(256) void swin_attn2_kernel(
    const char* __restrict__ kvg, const unsigned int* __restrict__ qg,
    const _Float16* __restrict__ w2T, const float* __restrict__ b2,
    const float* __restrict__ tblP, float* __restrict__ out)
{
    __shared__ __align__(16) char smem[27136];
    _Float16* Kb = (_Float16*)smem;
    _Float16* Vt = (_Float16*)(smem + 13312);

    const int tid = threadIdx.x;
    const int wv = tid >> 6, lane = tid & 63;
    const int lr = lane & 15, lg = lane >> 4;
    const int gid = blockIdx.x;
    const int b = gid >> 6, wh = (gid >> 3) & 7, ww = gid & 7;
    const f32x4 fz = {0.f, 0.f, 0.f, 0.f};

    // issue blob loads first (HBM/L3 latency overlaps the per-lane loads below)
    float4 stg[7];
    const char* src = kvg + (size_t)gid * KV_BYTES;
    #pragma unroll
    for (int i = 0; i < 7; ++i) {
        const int idx = tid + i * 256;
        if (idx < 1696) stg[i] = *(const float4*)(src + idx * 16);
    }
    // per-lane Q frags + bias rows + w2 first-head frags (independent of blob)
    u32x4 qd[3];
    {
        const unsigned int* qsrc = qg + (size_t)gid * 3072 + tid * 12;
        qd[0] = *(const u32x4*)(qsrc + 0);
        qd[1] = *(const u32x4*)(qsrc + 4);
        qd[2] = *(const u32x4*)(qsrc + 8);
    }
    f32x4 tv[4];
    {
        const float* tblv = tblP + ((wh == 7) ? 4096 : 0) + ((ww == 7) ? 8192 : 0)
                          + (wv * 16 + lr) * 64 + lg * 4;
        #pragma unroll
        for (int i = 0; i < 4; ++i)
            tv[i] = *(const f32x4*)(tblv + i * 16);
    }
    #pragma unroll
    for (int i = 0; i < 7; ++i) {
        const int idx = tid + i * 256;
        if (idx < 1696) *(float4*)(smem + idx * 16) = stg[i];
    }
    __syncthreads();

    f32x4 accO[6];
    #pragma unroll
    for (int i = 0; i < 6; ++i) accO[i] = fz;

    #pragma unroll
    for (int h = 0; h < 3; ++h) {
        const half8_t qv = __builtin_bit_cast(half8_t, qd[h]);
        f32x4 s[4];
        #pragma unroll
        for (int i = 0; i < 4; ++i) {
            const int col = (h * 32 + lg * 8) ^ ((i & 1) << 4);
            half8_t kf = *(const half8_t*)(Kb + (i * 16 + lr) * 104 + col);
            s[i] = __builtin_amdgcn_mfma_f32_16x16x32_f16(kf, qv, tv[i], 0, 0, 0);
        }
        half8_t vf00 = *(const half8_t*)(Vt + (h * 32 + lr) * 72 + lg * 8);
        half8_t vf01 = *(const half8_t*)(Vt + (h * 32 + lr) * 72 + 32 + lg * 8);
        half8_t vf10 = *(const half8_t*)(Vt + (h * 32 + 16 + lr) * 72 + lg * 8);
        half8_t vf11 = *(const half8_t*)(Vt + (h * 32 + 16 + lr) * 72 + 32 + lg * 8);
        half8_t wf[6];
        #pragma unroll
        for (int nt = 0; nt < 6; ++nt)
            wf[nt] = *(const half8_t*)(w2T + (nt * 16 + lr) * 96 + h * 32 + lg * 8);

        float ps[4];
        #pragma unroll
        for (int i = 0; i < 4; ++i) {
            float a0 = exp2f(s[i][0]), a1 = exp2f(s[i][1]);
            float a2 = exp2f(s[i][2]), a3 = exp2f(s[i][3]);
            s[i][0] = a0; s[i][1] = a1; s[i][2] = a2; s[i][3] = a3;
            ps[i] = (a0 + a1) + (a2 + a3);
        }
        float sum = (ps[0] + ps[1]) + (ps[2] + ps[3]);
        const u32x4 p0 = {pkrtz(s[0][0], s[0][1]), pkrtz(s[0][2], s[0][3]),
                          pkrtz(s[1][0], s[1][1]), pkrtz(s[1][2], s[1][3])};
        const u32x4 p1 = {pkrtz(s[2][0], s[2][1]), pkrtz(s[2][2], s[2][3]),
                          pkrtz(s[3][0], s[3][1]), pkrtz(s[3][2], s[3][3])};
        const half8_t pf0 = __builtin_bit_cast(half8_t, p0);
        const half8_t pf1 = __builtin_bit_cast(half8_t, p1);
        sum += __shfl_xor(sum, 16);
        sum += __shfl_xor(sum, 32);
        f32x4 o0 = __builtin_amdgcn_mfma_f32_16x16x32_f16(vf00, pf0, fz, 0, 0, 0);
        o0 = __builtin_amdgcn_mfma_f32_16x16x32_f16(vf01, pf1, o0, 0, 0, 0);
        f32x4 o1 = __builtin_amdgcn_mfma_f32_16x16x32_f16(vf10, pf0, fz, 0, 0, 0);
        o1 = __builtin_amdgcn_mfma_f32_16x16x32_f16(vf11, pf1, o1, 0, 0, 0);
        const float inv = 1.0f / sum;
        const u32x4 od = {pkrtz(o0[0] * inv, o0[1] * inv), pkrtz(o0[2] * inv, o0[3] * inv),
                          pkrtz(o1[0] * inv, o1[1] * inv), pkrtz(o1[2] * inv, o1[3] * inv)};
        const half8_t of = __builtin_bit_cast(half8_t, od);
        #pragma unroll
        for (int nt = 0; nt < 6; ++nt)
            accO[nt] = __builtin_amdgcn_mfma_f32_16x16x32_f16(of, wf[nt], accO[nt], 0, 0, 0);
    }

    float b2v[6];
    #pragma unroll
    for (int nt = 0; nt < 6; ++nt) b2v[nt] = b2[nt * 16 + lr];
    #pragma unroll
    for (int r = 0; r < 4; ++r) {
        const int row = wv * 16 + lg * 4 + r;
        if (row < 49) {
            const int m1 = row / 7, m2 = row % 7;
            int oi = wh * 7 + m1 + 3; if (oi >= 56) oi -= 56;
            int oj = ww * 7 + m2 + 3; if (oj >= 56) oj -= 56;
            float* op = out + ((size_t)b * 3136 + oi * 56 + oj) * 96;
            #pragma unroll
            for (int nt = 0; nt < 6; ++nt)
                op[nt * 16 + lr] = accO[nt][r] + b2v[nt];
        }
    }
}

// ======== Fallback: R9 fused kernel (used when ws_size < WS_NEED) ========
__global__ __launch_bounds__(256) void swin_attn_kernel(
    const float* __restrict__ x,
    const _Float16* __restrict__ w1T,
    const _Float16* __restrict__ w2T,
    const float* __restrict__ b1p,
    const float* __restrict__ b2,
    const float* __restrict__ tblP,
    float* __restrict__ out)
{
    __shared__ __align__(16) char smem[27136];
    _Float16* Kb = (_Float16*)smem;
    _Float16* Vt = (_Float16*)(smem + 13312);
    _Float16* Xs = Kb;

    const int tid = threadIdx.x;
    const int wv = tid >> 6, lane = tid & 63;
    const int lr = lane & 15, lg = lane >> 4;
    const int gid = blockIdx.x;
    const int b = gid >> 6, wh = (gid >> 3) & 7, ww = gid & 7;
    const f32x4 fz = {0.f, 0.f, 0.f, 0.f};

    {
        const int p = tid >> 2, sub = tid & 3;
        const float* xrow = nullptr;
        if (p < 49) {
            const int m1 = p / 7, m2 = p % 7;
            int rr = wh * 7 + m1 + 4; if (rr >= 56) rr -= 56;
            int cc = ww * 7 + m2 + 4; if (cc >= 56) cc -= 56;
            xrow = x + ((size_t)b * 3136 + rr * 56 + cc) * 96;
        }
        #pragma unroll
        for (int j = 0; j < 6; ++j) {
            const int e = sub * 24 + j * 4;
            half4_t hv = {(_Float16)0.f, (_Float16)0.f, (_Float16)0.f, (_Float16)0.f};
            if (p < 49) {
                const float4 v = *(const float4*)(xrow + e);
                hv[0] = (_Float16)v.x; hv[1] = (_Float16)v.y;
                hv[2] = (_Float16)v.z; hv[3] = (_Float16)v.w;
            }
            *(half4_t*)(Xs + p * 104 + e) = hv;
        }
    }
    __syncthreads();
    half8_t xa[4][3], xq[3];
    #pragma unroll
    for (int mt = 0; mt < 4; ++mt)
        #pragma unroll
        for (int kt = 0; kt < 3; ++kt)
            xa[mt][kt] = *(const half8_t*)(Xs + (mt * 16 + lr) * 104 + kt * 32 + lg * 8);
    #pragma unroll
    for (int kt = 0; kt < 3; ++kt)
        xq[kt] = *(const half8_t*)(Xs + (wv * 16 + lr) * 104 + kt * 32 + lg * 8);
    __syncthreads();
    {
        half8_t bf0, bf1, bf2; float bv;
        {
            const int nt0 = 6 + wv;
            bf0 = *(const half8_t*)(w1T + (nt0 * 16 + lr) * 96 + lg * 8);
            bf1 = *(const half8_t*)(w1T + (nt0 * 16 + lr) * 96 + 32 + lg * 8);
            bf2 = *(const half8_t*)(w1T + (nt0 * 16 + lr) * 96 + 64 + lg * 8);
            bv = b1p[nt0 * 16 + lr];
        }
        #pragma unroll
        for (int t = 0; t < 3; ++t) {
            const int nt = 6 + wv + 4 * t;
            half8_t nf0 = bf0, nf1 = bf1, nf2 = bf2; float nbv = bv;
            if (t < 2) {
                const int ntn = nt + 4;
                nf0 = *(const half8_t*)(w1T + (ntn * 16 + lr) * 96 + lg * 8);
                nf1 = *(const half8_t*)(w1T + (ntn * 16 + lr) * 96 + 32 + lg * 8);
                nf2 = *(const half8_t*)(w1T + (ntn * 16 + lr) * 96 + 64 + lg * 8);
                nbv = b1p[ntn * 16 + lr];
            }
            #pragma unroll
            for (int mt = 0; mt < 4; ++mt) {
                f32x4 acc = fz;
                acc = __builtin_amdgcn_mfma_f32_16x16x32_f16(xa[mt][0], bf0, acc, 0, 0, 0);
                acc = __builtin_amdgcn_mfma_f32_16x16x32_f16(xa[mt][1], bf1, acc, 0, 0, 0);
                acc = __builtin_amdgcn_mfma_f32_16x16x32_f16(xa[mt][2], bf2, acc, 0, 0, 0);
                if (nt < 12) {
                    const int kc = ((nt - 6) * 16 + lr) ^ ((lg & 1) << 4);
                    #pragma unroll
                    for (int r = 0; r < 4; ++r) {
                        const int krow = ((mt >> 1) * 2 + (lg & 1)) * 16
                                       + ((mt * 2 + (lg >> 1)) & 3) * 4 + r;
                        Kb[krow * 104 + kc] = (_Float16)(acc[r] + bv);
                    }
                } else {
                    const int nv = nt - 12;
                    const int hh = nv >> 1, eta = nv & 1;
                    const int vrow = hh * 32 + ((lr >> 2) & 1) * 16
                                   + (((eta << 1) + (lr >> 3)) & 3) * 4 + (lr & 3);
                    half4_t hv;
                    #pragma unroll
                    for (int r = 0; r < 4; ++r) hv[r] = (_Float16)(acc[r] + bv);
                    *(half4_t*)(Vt + vrow * 72 + mt * 16 + lg * 4) = hv;
                }
            }
            bf0 = nf0; bf1 = nf1; bf2 = nf2; bv = nbv;
        }
    }
    unsigned int qpk[3][4];
    {
        half8_t af0 = *(const half8_t*)(w1T + lr * 96 + lg * 8);
        half8_t af1 = *(const half8_t*)(w1T + lr * 96 + 32 + lg * 8);
        half8_t af2 = *(const half8_t*)(w1T + lr * 96 + 64 + lg * 8);
        #pragma unroll
        for (int f = 0; f < 6; ++f) {
            half8_t n0 = af0, n1 = af1, n2 = af2;
            if (f < 5) {
                n0 = *(const half8_t*)(w1T + ((f + 1) * 16 + lr) * 96 + lg * 8);
                n1 = *(const half8_t*)(w1T + ((f + 1) * 16 + lr) * 96 + 32 + lg * 8);
                n2 = *(const half8_t*)(w1T + ((f + 1) * 16 + lr) * 96 + 64 + lg * 8);
            }
            f32x4 acc = fz;
            acc = __builtin_amdgcn_mfma_f32_16x16x32_f16(af0, xq[0], acc, 0, 0, 0);
            acc = __builtin_amdgcn_mfma_f32_16x16x32_f16(af1, xq[1], acc, 0, 0, 0);
            acc = __builtin_amdgcn_mfma_f32_16x16x32_f16(af2, xq[2], acc, 0, 0, 0);
            const float4 bq = *(const float4*)(b1p + (f >> 1) * 32 + lg * 8 + (f & 1) * 4);
            qpk[f >> 1][(f & 1) * 2 + 0] = pack2h(acc[0] + bq.x, acc[1] + bq.y);
            qpk[f >> 1][(f & 1) * 2 + 1] = pack2h(acc[2] + bq.z, acc[3] + bq.w);
            af0 = n0; af1 = n1; af2 = n2;
        }
    }
    f32x4 tv[4];
    {
        const float* tblv = tblP + ((wh == 7) ? 4096 : 0) + ((ww == 7) ? 8192 : 0)
                          + (wv * 16 + lr) * 64 + lg * 4;
        #pragma unroll
        for (int i = 0; i < 4; ++i)
            tv[i] = *(const f32x4*)(tblv + i * 16);
    }
    __syncthreads();
    f32x4 accO[6];
    #pragma unroll
    for (int i = 0; i < 6; ++i) accO[i] = fz;
    #pragma unroll
    for (int h = 0; h < 3; ++h) {
        const u32x4 qdv = {qpk[h][0], qpk[h][1], qpk[h][2], qpk[h][3]};
        const half8_t qv = __builtin_bit_cast(half8_t, qdv);
        f32x4 s[4];
        #pragma unroll
        for (int i = 0; i < 4; ++i) {
            const int col = (h * 32 + lg * 8) ^ ((i & 1) << 4);
            half8_t kf = *(const half8_t*)(Kb + (i * 16 + lr) * 104 + col);
            s[i] = __builtin_amdgcn_mfma_f32_16x16x32_f16(kf, qv, tv[i], 0, 0, 0);
        }
        half8_t vf00 = *(const half8_t*)(Vt + (h * 32 + lr) * 72 + lg * 8);
        half8_t vf01 = *(const half8_t*)(Vt + (h * 32 + lr) * 72 + 32 + lg * 8);
        half8_t vf10 = *(const half8_t*)(Vt + (h * 32 + 16 + lr) * 72 + lg * 8);
        half8_t vf11 = *(const half8_t*)(Vt + (h * 32 + 16 + lr) * 72 + 32 + lg * 8);
        half8_t wf[6];
        #pragma unroll
        for (int nt = 0; nt < 6; ++nt)
            wf[nt] = *(const half8_t*)(w2T + (nt * 16 + lr) * 96 + h * 32 + lg * 8);
        float ps[4];
        #pragma unroll
        for (int i = 0; i < 4; ++i) {
            float a0 = exp2f(s[i][0]), a1 = exp2f(s[i][1]);
            float a2 = exp2f(s[i][2]), a3 = exp2f(s[i][3]);
            s[i][0] = a0; s[i][1] = a1; s[i][2] = a2; s[i][3] = a3;
            ps[i] = (a0 + a1) + (a2 + a3);
        }
        float sum = (ps[0] + ps[1]) + (ps[2] + ps[3]);
        const u32x4 p0 = {pkrtz(s[0][0], s[0][1]), pkrtz(s[0][2], s[0][3]),
                          pkrtz(s[1][0], s[1][1]), pkrtz(s[1][2], s[1][3])};
        const u32x4 p1 = {pkrtz(s[2][0], s[2][1]), pkrtz(s[2][2], s[2][3]),
                          pkrtz(s[3][0], s[3][1]), pkrtz(s[3][2], s[3][3])};
        const half8_t pf0 = __builtin_bit_cast(half8_t, p0);
        const half8_t pf1 = __builtin_bit_cast(half8_t, p1);
        sum += __shfl_xor(sum, 16);
        sum += __shfl_xor(sum, 32);
        f32x4 o0 = __builtin_amdgcn_mfma_f32_16x16x32_f16(vf00, pf0, fz, 0, 0, 0);
        o0 = __builtin_amdgcn_mfma_f32_16x16x32_f16(vf01, pf1, o0, 0, 0, 0);
        f32x4 o1 = __builtin_amdgcn_mfma_f32_16x16x32_f16(vf10, pf0, fz, 0, 0, 0);
        o1 = __builtin_amdgcn_mfma_f32_16x16x32_f16(vf11, pf1, o1, 0, 0, 0);
        const float inv = 1.0f / sum;
        const u32x4 od = {pkrtz(o0[0] * inv, o0[1] * inv), pkrtz(o0[2] * inv, o0[3] * inv),
                          pkrtz(o1[0] * inv, o1[1] * inv), pkrtz(o1[2] * inv, o1[3] * inv)};
        const half8_t of = __builtin_bit_cast(half8_t, od);
        #pragma unroll
        for (int nt = 0; nt < 6; ++nt)
            accO[nt] = __builtin_amdgcn_mfma_f32_16x16x32_f16(of, wf[nt], accO[nt], 0, 0, 0);
    }
    float b2v[6];
    #pragma unroll
    for (int nt = 0; nt < 6; ++nt) b2v[nt] = b2[nt * 16 + lr];
    #pragma unroll
    for (int r = 0; r < 4; ++r) {
        const int row = wv * 16 + lg * 4 + r;
        if (row < 49) {
            const int m1 = row / 7, m2 = row % 7;
            int oi = wh * 7 + m1 + 3; if (oi >= 56) oi -= 56;
            int oj = ww * 7 + m2 + 3; if (oj >= 56) oj -= 56;
            float* op = out + ((size_t)b * 3136 + oi * 56 + oj) * 96;
            #pragma unroll
            for (int nt = 0; nt < 6; ++nt)
                op[nt * 16 + lr] = accO[nt][r] + b2v[nt];
        }
    }
}

extern "C" void kernel_launch(void* const* d_in, const int* in_sizes, int n_in,
                              void* d_out, int out_size, void* d_ws, size_t ws_size,
                              hipStream_t stream) {
    const float* x    = (const float*)d_in[0];
    const float* w1   = (const float*)d_in[1];
    const float* b1   = (const float*)d_in[2];
    const float* w2   = (const float*)d_in[3];
    const float* b2   = (const float*)d_in[4];
    const float* relb = (const float*)d_in[5];
    float* out = (float*)d_out;

    _Float16* w1T  = (_Float16*)((char*)d_ws);
    _Float16* w2T  = (_Float16*)((char*)d_ws + WS_W2T);
    float*    b1p  = (float*)((char*)d_ws + WS_B1P);
    float*    tblP = (float*)((char*)d_ws + WS_TBL);

    swin_prep_kernel<<<210, 256, 0, stream>>>(w1, b1, w2, relb, w1T, w2T, b1p, tblP);

    if (ws_size >= WS_NEED) {
        char*         kvg = (char*)d_ws + WS_KVG;
        unsigned int* qg  = (unsigned int*)((char*)d_ws + WS_QG);
        swin_qkv_kernel<<<4096, 256, 0, stream>>>(x, w1T, b1p, kvg, qg);
        swin_attn2_kernel<<<4096, 256, 0, stream>>>(kvg, qg, w2T, b2, tblP, out);
    } else {
        swin_attn_kernel<<<4096, 256, 0, stream>>>(x, w1T, w2T, b1p, b2, tblP, out);
    }
}

// Round 11
// 93.489 us; speedup vs baseline: 1.7669x; 1.7669x over previous
//
#include <hip/hip_runtime.h>
#include <hip/hip_fp16.h>

typedef _Float16 half8_t __attribute__((ext_vector_type(8)));
typedef _Float16 half4_t __attribute__((ext_vector_type(4)));
typedef float f32x4 __attribute__((ext_vector_type(4)));
typedef unsigned int u32x4 __attribute__((ext_vector_type(4)));

// ws: [0,55296)      w1T fp16 [288][96]; rows 0..95 = Q cols PERMUTED, scaled qs*log2e
//     [55296,73728)  w2T fp16 [96][96]
//     [73728,74880)  b1p f32 [288]
//     [74880,140416) tblP f32 [4][64][64] (permuted, *log2e)
#define WS_W2T 55296
#define WS_B1P 73728
#define WS_TBL 74880

__global__ __launch_bounds__(256) void swin_prep_kernel(
    const float* __restrict__ w1, const float* __restrict__ b1,
    const float* __restrict__ w2, const float* __restrict__ relb,
    _Float16* __restrict__ w1T, _Float16* __restrict__ w2T,
    float* __restrict__ b1p, float* __restrict__ tblP)
{
    int idx = blockIdx.x * 256 + threadIdx.x;
    const float L2E = 1.4426950408889634f;
    const float qs2 = 0.17677669529663687f * L2E;
    if (idx < 27648) {
        int jp = idx / 96, k = idx % 96;
        float v;
        if (jp < 96) {
            int f = jp >> 4, m = jp & 15;
            int cq = (f >> 1) * 32 + (m >> 2) * 8 + (f & 1) * 4 + (m & 3);
            v = w1[k * 288 + cq * 3] * qs2;
        } else {
            int jo = (jp % 96) * 3 + (jp / 96);
            v = w1[k * 288 + jo];
        }
        w1T[idx] = (_Float16)v;
    } else if (idx < 36864) {
        int i2 = idx - 27648;
        int n = i2 / 96, k = i2 % 96;
        w2T[i2] = (_Float16)w2[k * 96 + n];
    } else if (idx < 37152) {
        int jp = idx - 36864;
        float v = b1[(jp % 96) * 3 + (jp / 96)];
        if (jp < 96) v *= qs2;
        b1p[jp] = v;
    } else if (idx < 53536) {
        int t = idx - 37152;
        int vv = t >> 12, q = (t >> 6) & 63, c = t & 63;
        int i = c >> 4, m = c & 15;
        int k = (i >> 1) * 32 + (m >> 2) * 8 + (i & 1) * 4 + (m & 3);
        float val = -1e30f;
        if (q < 49 && k < 49) {
            val = relb[q * 49 + k] * L2E;
            if ((vv & 1) && ((q >= 28) != (k >= 28))) val = -1e30f;
            if ((vv & 2) && (((q % 7) >= 4) != ((k % 7) >= 4))) val = -1e30f;
        }
        tblP[t] = val;
    }
}

__device__ __forceinline__ unsigned int pack2h(float a, float b) {
    union { _Float16 h[2]; unsigned int u; } p;
    p.h[0] = (_Float16)a; p.h[1] = (_Float16)b;
    return p.u;
}
__device__ __forceinline__ unsigned int pkrtz(float a, float b) {
    return __builtin_bit_cast(unsigned int, __builtin_amdgcn_cvt_pkrtz(a, b));
}

// Block = FOUR consecutive windows (same b, same wh; ww = ww0..ww0+3). 4 waves.
// Per window: fragread+QKV -> [barrier A] -> stage_x(next) || head-loop -> [barrier B].
// Dedicated Xs buffer (no aliasing) => 2 barriers/window; x-latency of windows 1..3
// hides under the previous head-loop; weights L1/L2-hot after window 0.
// LDS 40448 B: Xs[64][104]@0, Kb[64][104]@13312, Vt[96][72]@26624 -> 4 blocks/CU.
__global__ __launch_bounds__(256) void swin_attn_kernel(
    const float* __restrict__ x,
    const _Float16* __restrict__ w1T,
    const _Float16* __restrict__ w2T,
    const float* __restrict__ b1p,
    const float* __restrict__ b2,
    const float* __restrict__ tblP,
    float* __restrict__ out)
{
    __shared__ __align__(16) char smem[40448];
    _Float16* Xs = (_Float16*)smem;            // [64][104]
    _Float16* Kb = (_Float16*)(smem + 13312);  // [64][104]
    _Float16* Vt = (_Float16*)(smem + 26624);  // [96][72]

    const int tid = threadIdx.x;
    const int wv = tid >> 6, lane = tid & 63;
    const int lr = lane & 15, lg = lane >> 4;

    const int gid0 = blockIdx.x * 4;           // first window of this block
    const int b = gid0 >> 6, wh = (gid0 >> 3) & 7, ww0 = gid0 & 7;
    const f32x4 fz = {0.f, 0.f, 0.f, 0.f};

    // staging constants (4 threads per row, 6 float4 each)
    const int sp = tid >> 2, ssub = tid & 3;
    int srr = 0, sm2 = 0;
    if (sp < 49) {
        const int m1 = sp / 7; sm2 = sp % 7;
        srr = wh * 7 + m1 + 4; if (srr >= 56) srr -= 56;
    }

    // ---- prologue: stage window 0 ----
    {
        const float* xrow = nullptr;
        if (sp < 49) {
            int cc = ww0 * 7 + sm2 + 4; if (cc >= 56) cc -= 56;
            xrow = x + ((size_t)b * 3136 + srr * 56 + cc) * 96;
        }
        #pragma unroll
        for (int j = 0; j < 6; ++j) {
            const int e = ssub * 24 + j * 4;
            half4_t hv = {(_Float16)0.f, (_Float16)0.f, (_Float16)0.f, (_Float16)0.f};
            if (sp < 49) {
                const float4 v = *(const float4*)(xrow + e);
                hv[0] = (_Float16)v.x; hv[1] = (_Float16)v.y;
                hv[2] = (_Float16)v.z; hv[3] = (_Float16)v.w;
            }
            *(half4_t*)(Xs + sp * 104 + e) = hv;
        }
    }
    __syncthreads();

    float b2v[6];
    #pragma unroll
    for (int nt = 0; nt < 6; ++nt) b2v[nt] = b2[nt * 16 + lr];

    #pragma unroll 1
    for (int n = 0; n < 4; ++n) {
        const int ww = ww0 + n;

        // ---- frag reads from Xs ----
        half8_t xa[4][3], xq[3];
        #pragma unroll
        for (int mt = 0; mt < 4; ++mt)
            #pragma unroll
            for (int kt = 0; kt < 3; ++kt)
                xa[mt][kt] = *(const half8_t*)(Xs + (mt * 16 + lr) * 104 + kt * 32 + lg * 8);
        #pragma unroll
        for (int kt = 0; kt < 3; ++kt)
            xq[kt] = *(const half8_t*)(Xs + (wv * 16 + lr) * 104 + kt * 32 + lg * 8);

        // ---- QKV: K,V (nt-split; permuted stores) ----
        #pragma unroll
        for (int t = 0; t < 3; ++t) {
            const int nt = 6 + wv + 4 * t;     // 6..17
            half8_t bf0 = *(const half8_t*)(w1T + (nt * 16 + lr) * 96 + lg * 8);
            half8_t bf1 = *(const half8_t*)(w1T + (nt * 16 + lr) * 96 + 32 + lg * 8);
            half8_t bf2 = *(const half8_t*)(w1T + (nt * 16 + lr) * 96 + 64 + lg * 8);
            const float bv = b1p[nt * 16 + lr];
            #pragma unroll
            for (int mt = 0; mt < 4; ++mt) {
                f32x4 acc = fz;
                acc = __builtin_amdgcn_mfma_f32_16x16x32_f16(xa[mt][0], bf0, acc, 0, 0, 0);
                acc = __builtin_amdgcn_mfma_f32_16x16x32_f16(xa[mt][1], bf1, acc, 0, 0, 0);
                acc = __builtin_amdgcn_mfma_f32_16x16x32_f16(xa[mt][2], bf2, acc, 0, 0, 0);
                if (nt < 12) {   // K: permuted rows, col^16 keyed on lg bit0
                    const int kc = ((nt - 6) * 16 + lr) ^ ((lg & 1) << 4);
                    #pragma unroll
                    for (int r = 0; r < 4; ++r) {
                        const int krow = ((mt >> 1) * 2 + (lg & 1)) * 16
                                       + ((mt * 2 + (lg >> 1)) & 3) * 4 + r;
                        Kb[krow * 104 + kc] = (_Float16)(acc[r] + bv);
                    }
                } else {         // V: e-row permuted
                    const int nv = nt - 12;
                    const int hh = nv >> 1, eta = nv & 1;
                    const int vrow = hh * 32 + ((lr >> 2) & 1) * 16
                                   + (((eta << 1) + (lr >> 3)) & 3) * 4 + (lr & 3);
                    half4_t hv;
                    #pragma unroll
                    for (int r = 0; r < 4; ++r) hv[r] = (_Float16)(acc[r] + bv);
                    *(half4_t*)(Vt + vrow * 72 + mt * 16 + lg * 4) = hv;
                }
            }
        }

        // ---- Q as QK B-frags in regs (permuted w1T rows) ----
        unsigned int qpk[3][4];
        #pragma unroll
        for (int f = 0; f < 6; ++f) {
            half8_t af0 = *(const half8_t*)(w1T + (f * 16 + lr) * 96 + lg * 8);
            half8_t af1 = *(const half8_t*)(w1T + (f * 16 + lr) * 96 + 32 + lg * 8);
            half8_t af2 = *(const half8_t*)(w1T + (f * 16 + lr) * 96 + 64 + lg * 8);
            f32x4 acc = fz;
            acc = __builtin_amdgcn_mfma_f32_16x16x32_f16(af0, xq[0], acc, 0, 0, 0);
            acc = __builtin_amdgcn_mfma_f32_16x16x32_f16(af1, xq[1], acc, 0, 0, 0);
            acc = __builtin_amdgcn_mfma_f32_16x16x32_f16(af2, xq[2], acc, 0, 0, 0);
            const float4 bq = *(const float4*)(b1p + (f >> 1) * 32 + lg * 8 + (f & 1) * 4);
            qpk[f >> 1][(f & 1) * 2 + 0] = pack2h(acc[0] + bq.x, acc[1] + bq.y);
            qpk[f >> 1][(f & 1) * 2 + 1] = pack2h(acc[2] + bq.z, acc[3] + bq.w);
        }

        // ---- bias/mask rows for this window ----
        f32x4 tv[4];
        {
            const float* tblv = tblP + ((wh == 7) ? 4096 : 0) + ((ww == 7) ? 8192 : 0)
                              + (wv * 16 + lr) * 64 + lg * 4;
            #pragma unroll
            for (int i = 0; i < 4; ++i)
                tv[i] = *(const f32x4*)(tblv + i * 16);
        }
        __syncthreads();   // barrier A: Kb/Vt ready; Xs frag-reads done everywhere

        // ---- stage next window's x into Xs (overlaps head-loop below) ----
        if (n < 3) {
            const float* xrow = nullptr;
            if (sp < 49) {
                int cc = (ww + 1) * 7 + sm2 + 4; if (cc >= 56) cc -= 56;
                xrow = x + ((size_t)b * 3136 + srr * 56 + cc) * 96;
            }
            #pragma unroll
            for (int j = 0; j < 6; ++j) {
                const int e = ssub * 24 + j * 4;
                half4_t hv = {(_Float16)0.f, (_Float16)0.f, (_Float16)0.f, (_Float16)0.f};
                if (sp < 49) {
                    const float4 v = *(const float4*)(xrow + e);
                    hv[0] = (_Float16)v.x; hv[1] = (_Float16)v.y;
                    hv[2] = (_Float16)v.z; hv[3] = (_Float16)v.w;
                }
                *(half4_t*)(Xs + sp * 104 + e) = hv;
            }
        }

        // ---- head-loop (wave-local) ----
        f32x4 accO[6];
        #pragma unroll
        for (int i = 0; i < 6; ++i) accO[i] = fz;

        #pragma unroll
        for (int h = 0; h < 3; ++h) {
            const u32x4 qd = {qpk[h][0], qpk[h][1], qpk[h][2], qpk[h][3]};
            const half8_t qv = __builtin_bit_cast(half8_t, qd);
            f32x4 s[4];
            #pragma unroll
            for (int i = 0; i < 4; ++i) {
                const int col = (h * 32 + lg * 8) ^ ((i & 1) << 4);
                half8_t kf = *(const half8_t*)(Kb + (i * 16 + lr) * 104 + col);
                s[i] = __builtin_amdgcn_mfma_f32_16x16x32_f16(kf, qv, tv[i], 0, 0, 0);
            }
            half8_t vf00 = *(const half8_t*)(Vt + (h * 32 + lr) * 72 + lg * 8);
            half8_t vf01 = *(const half8_t*)(Vt + (h * 32 + lr) * 72 + 32 + lg * 8);
            half8_t vf10 = *(const half8_t*)(Vt + (h * 32 + 16 + lr) * 72 + lg * 8);
            half8_t vf11 = *(const half8_t*)(Vt + (h * 32 + 16 + lr) * 72 + 32 + lg * 8);
            half8_t wf[6];
            #pragma unroll
            for (int nt = 0; nt < 6; ++nt)
                wf[nt] = *(const half8_t*)(w2T + (nt * 16 + lr) * 96 + h * 32 + lg * 8);

            float ps[4];
            #pragma unroll
            for (int i = 0; i < 4; ++i) {
                float a0 = exp2f(s[i][0]), a1 = exp2f(s[i][1]);
                float a2 = exp2f(s[i][2]), a3 = exp2f(s[i][3]);
                s[i][0] = a0; s[i][1] = a1; s[i][2] = a2; s[i][3] = a3;
                ps[i] = (a0 + a1) + (a2 + a3);
            }
            float sum = (ps[0] + ps[1]) + (ps[2] + ps[3]);
            const u32x4 p0 = {pkrtz(s[0][0], s[0][1]), pkrtz(s[0][2], s[0][3]),
                              pkrtz(s[1][0], s[1][1]), pkrtz(s[1][2], s[1][3])};
            const u32x4 p1 = {pkrtz(s[2][0], s[2][1]), pkrtz(s[2][2], s[2][3]),
                              pkrtz(s[3][0], s[3][1]), pkrtz(s[3][2], s[3][3])};
            const half8_t pf0 = __builtin_bit_cast(half8_t, p0);
            const half8_t pf1 = __builtin_bit_cast(half8_t, p1);
            sum += __shfl_xor(sum, 16);
            sum += __shfl_xor(sum, 32);
            f32x4 o0 = __builtin_amdgcn_mfma_f32_16x16x32_f16(vf00, pf0, fz, 0, 0, 0);
            o0 = __builtin_amdgcn_mfma_f32_16x16x32_f16(vf01, pf1, o0, 0, 0, 0);
            f32x4 o1 = __builtin_amdgcn_mfma_f32_16x16x32_f16(vf10, pf0, fz, 0, 0, 0);
            o1 = __builtin_amdgcn_mfma_f32_16x16x32_f16(vf11, pf1, o1, 0, 0, 0);
            const float inv = 1.0f / sum;
            const u32x4 od = {pkrtz(o0[0] * inv, o0[1] * inv), pkrtz(o0[2] * inv, o0[3] * inv),
                              pkrtz(o1[0] * inv, o1[1] * inv), pkrtz(o1[2] * inv, o1[3] * inv)};
            const half8_t of = __builtin_bit_cast(half8_t, od);
            #pragma unroll
            for (int nt = 0; nt < 6; ++nt)
                accO[nt] = __builtin_amdgcn_mfma_f32_16x16x32_f16(of, wf[nt], accO[nt], 0, 0, 0);
        }

        // ---- store (+3,+3) rolled, bias ----
        #pragma unroll
        for (int r = 0; r < 4; ++r) {
            const int row = wv * 16 + lg * 4 + r;
            if (row < 49) {
                const int m1 = row / 7, m2 = row % 7;
                int oi = wh * 7 + m1 + 3; if (oi >= 56) oi -= 56;
                int oj = ww * 7 + m2 + 3; if (oj >= 56) oj -= 56;
                float* op = out + ((size_t)b * 3136 + oi * 56 + oj) * 96;
                #pragma unroll
                for (int nt = 0; nt < 6; ++nt)
                    op[nt * 16 + lr] = accO[nt][r] + b2v[nt];
            }
        }
        __syncthreads();   // barrier B: Xs(n+1) staged; Kb/Vt reads done
    }
}

extern "C" void kernel_launch(void* const* d_in, const int* in_sizes, int n_in,
                              void* d_out, int out_size, void* d_ws, size_t ws_size,
                              hipStream_t stream) {
    const float* x    = (const float*)d_in[0];
    const float* w1   = (const float*)d_in[1];
    const float* b1   = (const float*)d_in[2];
    const float* w2   = (const float*)d_in[3];
    const float* b2   = (const float*)d_in[4];
    const float* relb = (const float*)d_in[5];
    float* out = (float*)d_out;

    _Float16* w1T  = (_Float16*)((char*)d_ws);
    _Float16* w2T  = (_Float16*)((char*)d_ws + WS_W2T);
    float*    b1p  = (float*)((char*)d_ws + WS_B1P);
    float*    tblP = (float*)((char*)d_ws + WS_TBL);

    swin_prep_kernel<<<210, 256, 0, stream>>>(w1, b1, w2, relb, w1T, w2T, b1p, tblP);
    swin_attn_kernel<<<1024, 256, 0, stream>>>(x, w1T, w2T, b1p, b2, tblP, out);
}

// Round 13
// 77.680 us; speedup vs baseline: 2.1265x; 1.2035x over previous
//
#include <hip/hip_runtime.h>
#include <hip/hip_fp16.h>

typedef _Float16 half8_t __attribute__((ext_vector_type(8)));
typedef _Float16 half4_t __attribute__((ext_vector_type(4)));
typedef float f32x4 __attribute__((ext_vector_type(4)));
typedef unsigned int u32x2 __attribute__((ext_vector_type(2)));

// ws: [0,55296)        w1T fp16 [288][96]  (Q rows pre-scaled by qs*log2e)
//     [55296,73728)    w2T fp16 [96][96]
//     [73728,74880)    b1p f32 [288]       (Q entries pre-scaled by qs*log2e)
//     [74880,140416)   tbl f32 [4][64][64] ((relbias+mask)*log2e, pad -1e30)
#define WS_W2T 55296
#define WS_B1P 73728
#define WS_TBL 74880

__global__ __launch_bounds__(256) void swin_prep_kernel(
    const float* __restrict__ w1, const float* __restrict__ b1,
    const float* __restrict__ w2, const float* __restrict__ relb,
    _Float16* __restrict__ w1T, _Float16* __restrict__ w2T,
    float* __restrict__ b1p, float* __restrict__ tbl)
{
    int idx = blockIdx.x * 256 + threadIdx.x;
    const float L2E = 1.4426950408889634f;
    const float qs2 = 0.17677669529663687f * L2E;   // 1/sqrt(32) * log2(e)
    if (idx < 27648) {
        int jp = idx / 96, k = idx % 96;
        int jo = (jp % 96) * 3 + (jp / 96);      // original col in w1
        float v = w1[k * 288 + jo];
        if (jp < 96) v *= qs2;                   // fold QK scale + log2e into Q
        w1T[idx] = (_Float16)v;
    } else if (idx < 36864) {
        int i2 = idx - 27648;
        int n = i2 / 96, k = i2 % 96;
        w2T[i2] = (_Float16)w2[k * 96 + n];
    } else if (idx < 37152) {
        int jp = idx - 36864;
        float v = b1[(jp % 96) * 3 + (jp / 96)];
        if (jp < 96) v *= qs2;
        b1p[jp] = v;
    } else if (idx < 37152 + 16384) {
        int t = idx - 37152;
        int v = t >> 12, q = (t >> 6) & 63, k = t & 63;
        float val = -1e30f;
        if (q < 49 && k < 49) {
            val = relb[q * 49 + k] * L2E;
            if ((v & 1) && ((q >= 28) != (k >= 28))) val = -1e30f;          // row mask
            if ((v & 2) && (((q % 7) >= 4) != ((k % 7) >= 4))) val = -1e30f; // col mask
        }
        tbl[t] = val;
    }
}

__device__ __forceinline__ unsigned int pkrtz(float a, float b) {    // packed f32->f16 RTZ
    return __builtin_bit_cast(unsigned int, __builtin_amdgcn_cvt_pkrtz(a, b));
}

// XOR swizzles (R5): flip col bit4 (16 fp16 = 32B) when row bit3 set.
__device__ __forceinline__ int swx(int row, int col) {   // Xq/Kb, stride 104
    return row * 104 + (col ^ ((row & 8) << 1));
}
__device__ __forceinline__ int swp(int row, int col) {   // Pw, stride 72
    return row * 72 + (col ^ ((row & 8) << 1));
}

// R5 base + grafts, normalization FIXED vs R12:
//   O is stored UNNORMALIZED; the `of` A-fragment (read per row = lr, which IS the
//   lane's softmax row) is scaled by (fp16)inv after the LDS read — correct row,
//   and the sum-shuffles now hide under the whole P->PV->O-store chain.
//   (R12's normalize-at-O-store used the wrong row's inv: PV C-layout rows are
//   lg*4+r, not lr -> inf/NaN leaked into valid rows.)
// LDS (49664 B, 3 blocks/CU):
//   Xq [64][104] fp16 : phase0 rolled-x, then Q rows (aliased), swizzled  @ 0
//   Kb [64][104] fp16 : K rows, swizzled                                  @ 13312
//   Vt [96][72]  fp16 : V transposed [e][token]                           @ 26624
//   Pb 4x[16][72] fp16: per-wave P / O, swizzled (wave-local, in-order DS) @ 40448
__global__ __launch_bounds__(256, 3) void swin_attn_kernel(
    const float* __restrict__ x,
    const _Float16* __restrict__ w1T,
    const _Float16* __restrict__ w2T,
    const float* __restrict__ b1p,
    const float* __restrict__ b2,
    const float* __restrict__ tbl,
    float* __restrict__ out)
{
    __shared__ __align__(16) char smem[49664];
    _Float16* Xq = (_Float16*)smem;
    _Float16* Kb = (_Float16*)(smem + 13312);
    _Float16* Vt = (_Float16*)(smem + 26624);
    _Float16* Pb = (_Float16*)(smem + 40448);

    const int tid = threadIdx.x;
    const int wv = tid >> 6, lane = tid & 63;
    const int lr = lane & 15, lg = lane >> 4;

    const int gid = blockIdx.x;
    const int b = gid >> 6, wh = (gid >> 3) & 7, ww = gid & 7;
    const f32x4 fz = {0.f, 0.f, 0.f, 0.f};

    // ---- phase 0: stage rolled x window -> Xq fp16 (rows 49..63 zeroed) ----
    {
        const int p = tid >> 2, sub = tid & 3;
        const float* xrow = nullptr;
        if (p < 49) {
            const int m1 = p / 7, m2 = p % 7;
            int rr = wh * 7 + m1 + 4; if (rr >= 56) rr -= 56;
            int cc = ww * 7 + m2 + 4; if (cc >= 56) cc -= 56;
            xrow = x + ((size_t)b * 3136 + rr * 56 + cc) * 96;
        }
        #pragma unroll
        for (int j = 0; j < 6; ++j) {
            const int e = sub * 24 + j * 4;
            half4_t hv = {(_Float16)0.f, (_Float16)0.f, (_Float16)0.f, (_Float16)0.f};
            if (p < 49) {
                const float4 v = *(const float4*)(xrow + e);
                hv[0] = (_Float16)v.x; hv[1] = (_Float16)v.y;
                hv[2] = (_Float16)v.z; hv[3] = (_Float16)v.w;
            }
            *(half4_t*)(Xq + swx(p, e)) = hv;
        }
    }
    __syncthreads();

    // ---- phase 0b: all 4 row-groups' A-frags -> regs; tbl row -> regs ----
    half8_t xa[4][3];
    #pragma unroll
    for (int mt = 0; mt < 4; ++mt)
        #pragma unroll
        for (int kt = 0; kt < 3; ++kt)
            xa[mt][kt] = *(const half8_t*)(Xq + swx(mt * 16 + lr, kt * 32 + lg * 8));

    const float* tblv = tbl + (((wh == 7) ? 1 : 0) + ((ww == 7) ? 2 : 0)) * 4096;
    f32x4 tv[4];
    {
        const int q = wv * 16 + lr;
        #pragma unroll
        for (int kt4 = 0; kt4 < 4; ++kt4)
            tv[kt4] = *(const f32x4*)(tblv + q * 64 + kt4 * 16 + lg * 4);
    }
    __syncthreads();   // A-frag reads complete before Q overwrites Xq

    // ---- phase 1: QKV, nt-split, software-pipelined weight loads ----
    {
        int nt = wv;
        half8_t bf0 = *(const half8_t*)(w1T + (nt * 16 + lr) * 96 + lg * 8);
        half8_t bf1 = *(const half8_t*)(w1T + (nt * 16 + lr) * 96 + 32 + lg * 8);
        half8_t bf2 = *(const half8_t*)(w1T + (nt * 16 + lr) * 96 + 64 + lg * 8);
        float bv = b1p[nt * 16 + lr];
        while (nt < 18) {
            const int ntn = nt + 4;
            half8_t nf0 = bf0, nf1 = bf1, nf2 = bf2; float nbv = bv;
            if (ntn < 18) {   // prefetch next iteration's weights
                nf0 = *(const half8_t*)(w1T + (ntn * 16 + lr) * 96 + lg * 8);
                nf1 = *(const half8_t*)(w1T + (ntn * 16 + lr) * 96 + 32 + lg * 8);
                nf2 = *(const half8_t*)(w1T + (ntn * 16 + lr) * 96 + 64 + lg * 8);
                nbv = b1p[ntn * 16 + lr];
            }
            #pragma unroll
            for (int mt = 0; mt < 4; ++mt) {
                f32x4 acc = fz;
                acc = __builtin_amdgcn_mfma_f32_16x16x32_f16(xa[mt][0], bf0, acc, 0, 0, 0);
                acc = __builtin_amdgcn_mfma_f32_16x16x32_f16(xa[mt][1], bf1, acc, 0, 0, 0);
                acc = __builtin_amdgcn_mfma_f32_16x16x32_f16(xa[mt][2], bf2, acc, 0, 0, 0);
                if (nt < 6) {
                    #pragma unroll
                    for (int r = 0; r < 4; ++r)
                        Xq[swx(mt * 16 + lg * 4 + r, nt * 16 + lr)] = (_Float16)(acc[r] + bv);
                } else if (nt < 12) {
                    #pragma unroll
                    for (int r = 0; r < 4; ++r)
                        Kb[swx(mt * 16 + lg * 4 + r, (nt - 6) * 16 + lr)] = (_Float16)(acc[r] + bv);
                } else {
                    half4_t hv;
                    #pragma unroll
                    for (int r = 0; r < 4; ++r) hv[r] = (_Float16)(acc[r] + bv);
                    *(half4_t*)(Vt + ((nt - 12) * 16 + lr) * 72 + mt * 16 + lg * 4) = hv;
                }
            }
            bf0 = nf0; bf1 = nf1; bf2 = nf2; bv = nbv;
            nt = ntn;
        }
    }
    __syncthreads();   // Q/K/V visible to all waves

    _Float16* Pw = Pb + wv * 1152;   // wave-local P/O [16][72]
    f32x4 accO[6];
    #pragma unroll
    for (int i = 0; i < 6; ++i) accO[i] = fz;

    #pragma unroll
    for (int h = 0; h < 3; ++h) {
        // ---- S^T = K · Q^T + tbl (C-operand): lane holds S[q][k=kt4*16+lg*4+r] ----
        half8_t qf = *(const half8_t*)(Xq + swx(wv * 16 + lr, h * 32 + lg * 8));
        f32x4 s[4];
        #pragma unroll
        for (int kt4 = 0; kt4 < 4; ++kt4) {
            half8_t kf = *(const half8_t*)(Kb + swx(kt4 * 16 + lr, h * 32 + lg * 8));
            s[kt4] = __builtin_amdgcn_mfma_f32_16x16x32_f16(kf, qf, tv[kt4], 0, 0, 0);
        }
        // issue w2T (global) + V (LDS) loads now; latency hides under softmax
        half8_t wf[6];
        #pragma unroll
        for (int nt = 0; nt < 6; ++nt)
            wf[nt] = *(const half8_t*)(w2T + (nt * 16 + lr) * 96 + h * 32 + lg * 8);
        half8_t vf00 = *(const half8_t*)(Vt + (h * 32 + lr) * 72 + lg * 8);
        half8_t vf01 = *(const half8_t*)(Vt + (h * 32 + lr) * 72 + 32 + lg * 8);
        half8_t vf10 = *(const half8_t*)(Vt + (h * 32 + 16 + lr) * 72 + lg * 8);
        half8_t vf11 = *(const half8_t*)(Vt + (h * 32 + 16 + lr) * 72 + 32 + lg * 8);

        // ---- max-free softmax in exp2 domain (scales pre-folded) ----
        float ps[4];
        #pragma unroll
        for (int kt4 = 0; kt4 < 4; ++kt4) {
            float a0 = exp2f(s[kt4][0]), a1 = exp2f(s[kt4][1]);
            float a2 = exp2f(s[kt4][2]), a3 = exp2f(s[kt4][3]);
            s[kt4][0] = a0; s[kt4][1] = a1; s[kt4][2] = a2; s[kt4][3] = a3;
            ps[kt4] = (a0 + a1) + (a2 + a3);
        }
        // store UNNORMALIZED P immediately (pkrtz); sum-shuffles overlap the
        // P-write -> PV-read -> O-write LDS chain
        #pragma unroll
        for (int kt4 = 0; kt4 < 4; ++kt4) {
            u32x2 pp = {pkrtz(s[kt4][0], s[kt4][1]), pkrtz(s[kt4][2], s[kt4][3])};
            *(half4_t*)(Pw + swp(lr, kt4 * 16 + lg * 4)) = __builtin_bit_cast(half4_t, pp);
        }
        float sum = (ps[0] + ps[1]) + (ps[2] + ps[3]);
        sum += __shfl_xor(sum, 16);
        sum += __shfl_xor(sum, 32);
        // ---- PV: O[q][e] (wave-local; unnormalized P -> unnormalized O) ----
        half8_t pf0 = *(const half8_t*)(Pw + swp(lr, lg * 8));
        half8_t pf1 = *(const half8_t*)(Pw + swp(lr, 32 + lg * 8));
        f32x4 o0 = __builtin_amdgcn_mfma_f32_16x16x32_f16(pf0, vf00, fz, 0, 0, 0);
        o0 = __builtin_amdgcn_mfma_f32_16x16x32_f16(pf1, vf01, o0, 0, 0, 0);
        f32x4 o1 = __builtin_amdgcn_mfma_f32_16x16x32_f16(pf0, vf10, fz, 0, 0, 0);
        o1 = __builtin_amdgcn_mfma_f32_16x16x32_f16(pf1, vf11, o1, 0, 0, 0);
        // store O UNNORMALIZED over P region (in-order DS per wave)
        #pragma unroll
        for (int r = 0; r < 4; ++r) {
            Pw[swp(lg * 4 + r, lr)]      = (_Float16)o0[r];
            Pw[swp(lg * 4 + r, 16 + lr)] = (_Float16)o1[r];
        }
        // ---- normalize the A-fragment: `of` row IS lr = this lane's softmax row ----
        half8_t of = *(const half8_t*)(Pw + swp(lr, lg * 8));
        {
            const _Float16 ih = (_Float16)(1.0f / sum);
            const half8_t iv = {ih, ih, ih, ih, ih, ih, ih, ih};
            of = of * iv;   // 4x v_pk_mul_f16
        }
        // ---- out-proj slice: accO += O_h @ W2[h*32:+32, :] ----
        #pragma unroll
        for (int nt = 0; nt < 6; ++nt)
            accO[nt] = __builtin_amdgcn_mfma_f32_16x16x32_f16(of, wf[nt], accO[nt], 0, 0, 0);
    }

    // ---- phase 3: store (+3,+3) rolled, bias ----
    float b2v[6];
    #pragma unroll
    for (int nt = 0; nt < 6; ++nt) b2v[nt] = b2[nt * 16 + lr];
    #pragma unroll
    for (int r = 0; r < 4; ++r) {
        const int row = wv * 16 + lg * 4 + r;
        if (row < 49) {
            const int m1 = row / 7, m2 = row % 7;
            int oi = wh * 7 + m1 + 3; if (oi >= 56) oi -= 56;
            int oj = ww * 7 + m2 + 3; if (oj >= 56) oj -= 56;
            float* op = out + ((size_t)b * 3136 + oi * 56 + oj) * 96;
            #pragma unroll
            for (int nt = 0; nt < 6; ++nt)
                op[nt * 16 + lr] = accO[nt][r] + b2v[nt];
        }
    }
}

extern "C" void kernel_launch(void* const* d_in, const int* in_sizes, int n_in,
                              void* d_out, int out_size, void* d_ws, size_t ws_size,
                              hipStream_t stream) {
    const float* x    = (const float*)d_in[0];
    const float* w1   = (const float*)d_in[1];
    const float* b1   = (const float*)d_in[2];
    const float* w2   = (const float*)d_in[3];
    const float* b2   = (const float*)d_in[4];
    const float* relb = (const float*)d_in[5];
    float* out = (float*)d_out;

    _Float16* w1T = (_Float16*)((char*)d_ws);
    _Float16* w2T = (_Float16*)((char*)d_ws + WS_W2T);
    float*    b1p = (float*)((char*)d_ws + WS_B1P);
    float*    tbl = (float*)((char*)d_ws + WS_TBL);

    swin_prep_kernel<<<210, 256, 0, stream>>>(w1, b1, w2, relb, w1T, w2T, b1p, tbl);
    swin_attn_kernel<<<4096, 256, 0, stream>>>(x, w1T, w2T, b1p, b2, tbl, out);
}